// Round 3
// baseline (114.514 us; speedup 1.0000x reference)
//
#include <hip/hip_runtime.h>

// RandomAttention: B=2, S=2048, NH=8, H=64, NKEYS=64, fp32.
// One wave per (b, q, head). Lane remap: g = lane>>4 (key group),
// c = lane&15 (float4 chunk of the 64-float row). Each 16-lane group
// owns one key row per iteration -> every K/V wave-load covers 4 full
// 256B rows. Scores finish with 4 intra-group DPP shuffles.
//
// R1 (kept): head-major XCD mapping (e = blockIdx.x & 7) pins each
// head's 2MB gather slice in one XCD's 4MB L2 (FETCH 60.6->16.4 MB).
//
// R3: R1/R2 both failed to keep loads in flight (VGPR 56->44: the
// compiler dissolved the prefetch at IR level; sched_barrier alone
// can't stop it). This version issues every K/V gather as
// asm volatile global_load_dwordx4 with "=v" outputs - unmovable,
// destinations must stay allocated - and hand-builds the counted-wait
// pipeline (AITER pattern, never vmcnt(0) until the last group):
//   boff[16] -> lgkmcnt(0) -> 16 K loads in flight
//   -> vmcnt(12/8/4/0)+sched_barrier, dots in groups of 4
//   -> 16 V loads in flight -> softmax (hides V latency)
//   -> vmcnt(12/8/4/0)+sched_barrier, PV in groups of 4.
// All compiler-issued loads (q, idx) are consumed BEFORE the first asm
// load so SIInsertWaitcnts never drains our pipeline with a stray
// vmcnt(0). exp2f with log2e folded into the q scale replaces __expf.

#define BB 2
#define SS 2048
#define NHH 8
#define HH 64
#define NKEYS 64

#define WAITV(N) asm volatile("s_waitcnt vmcnt(" #N ")" ::: "memory"); \
                 __builtin_amdgcn_sched_barrier(0)

__global__ __launch_bounds__(256, 4) void rand_attn_kernel(
    const float* __restrict__ q, const float* __restrict__ k,
    const float* __restrict__ v, const int* __restrict__ idx,
    float* __restrict__ out) {
  const int warp = threadIdx.x >> 6;
  const int lane = threadIdx.x & 63;
  const int g = lane >> 4;   // key group 0..3 (key n == 4*j + g)
  const int c = lane & 15;   // float4 chunk within the 64-float row

  // Head == XCD (blocks dispatch round-robin over 8 XCDs).
  const int e = blockIdx.x & 7;                     // head
  const int bq = ((blockIdx.x >> 3) << 2) + warp;   // b*S + s, 4 per block
  const int b = bq >> 11;                           // S = 2048

  // q chunk for this lane (replicated across the 4 groups).
  // Scale folds 1/sqrt(64) * log2(e) so scores are in exp2 domain.
  const float* qrow = q + ((size_t)bq * NHH + e) * HH;
  float4 q4 = ((const float4*)qrow)[c];
  const float qs = 0.125f * 1.44269504088896f;
  q4.x *= qs; q4.y *= qs; q4.z *= qs; q4.w *= qs;   // consumes q load NOW

  // Lane n holds idx[bq, n] (coalesced 256B load).
  const int myidx = idx[(size_t)bq * NKEYS + lane];
  const float* kb = k + (size_t)b * (SS * NHH * HH);
  const float* vb = v + (size_t)b * (SS * NHH * HH);
  const int co = (e << 4) + c;   // within-row float4 offset: e*16 + c

  // Phase 0: all 16 key-row BYTE offsets. Row base for key index vi is
  // (vi*NHH + e)*HH floats; float4 unit offset = vi*128 + co; *16 bytes.
  int boff[16];
#pragma unroll
  for (int j = 0; j < 16; ++j) {
    const int n = 4 * j + g;
    const int vi = __builtin_amdgcn_ds_bpermute(n << 2, myidx);
    boff[j] = ((vi << 7) + co) << 4;
  }
  // Drain bpermutes (and any straggler compiler loads) before the
  // hand-issued pipeline starts.
  asm volatile("s_waitcnt vmcnt(0) lgkmcnt(0)" ::: "memory");
  __builtin_amdgcn_sched_barrier(0);

  // Phase 1a: ALL 16 K loads in flight (compiler cannot sink asm).
  float4 k4[16];
#pragma unroll
  for (int j = 0; j < 16; ++j) {
    asm volatile("global_load_dwordx4 %0, %1, %2"
                 : "=v"(k4[j]) : "v"(boff[j]), "s"(kb));
  }

  // Phase 1b: dots in groups of 4 under counted waits.
  float sc[16];
#pragma unroll
  for (int grp = 0; grp < 4; ++grp) {
    switch (grp) {  // literal vmcnt immediates
      case 0: WAITV(12); break;
      case 1: WAITV(8);  break;
      case 2: WAITV(4);  break;
      case 3: WAITV(0);  break;
    }
#pragma unroll
    for (int u = 0; u < 4; ++u) {
      const int j = 4 * grp + u;
      float t = k4[j].x * q4.x + k4[j].y * q4.y + k4[j].z * q4.z +
                k4[j].w * q4.w;
      t += __shfl_xor(t, 1, 64);   // intra-group (16-lane) reduce: DPP
      t += __shfl_xor(t, 2, 64);
      t += __shfl_xor(t, 4, 64);
      t += __shfl_xor(t, 8, 64);
      sc[j] = t;
    }
  }

  // Phase 2a: ALL 16 V loads in flight; softmax below hides them.
  float4 vv[16];
#pragma unroll
  for (int j = 0; j < 16; ++j) {
    asm volatile("global_load_dwordx4 %0, %1, %2"
                 : "=v"(vv[j]) : "v"(boff[j]), "s"(vb));
  }
  __builtin_amdgcn_sched_barrier(0);

  // Phase 2b: softmax over all 64 keys (exp2 domain).
  float m = sc[0];
#pragma unroll
  for (int j = 1; j < 16; ++j) m = fmaxf(m, sc[j]);
  m = fmaxf(m, __shfl_xor(m, 16, 64));
  m = fmaxf(m, __shfl_xor(m, 32, 64));
  float ssum = 0.f;
#pragma unroll
  for (int j = 0; j < 16; ++j) {
    sc[j] = exp2f(sc[j] - m);
    ssum += sc[j];
  }
  ssum += __shfl_xor(ssum, 16, 64);
  ssum += __shfl_xor(ssum, 32, 64);
  const float inv = __builtin_amdgcn_rcpf(ssum);  // wave-uniform

  // Phase 3: PV in groups of 4 under counted waits.
  float4 acc = make_float4(0.f, 0.f, 0.f, 0.f);
#pragma unroll
  for (int grp = 0; grp < 4; ++grp) {
    switch (grp) {
      case 0: WAITV(12); break;
      case 1: WAITV(8);  break;
      case 2: WAITV(4);  break;
      case 3: WAITV(0);  break;
    }
#pragma unroll
    for (int u = 0; u < 4; ++u) {
      const int j = 4 * grp + u;
      acc.x += sc[j] * vv[j].x;
      acc.y += sc[j] * vv[j].y;
      acc.z += sc[j] * vv[j].z;
      acc.w += sc[j] * vv[j].w;
    }
  }

  // Cross-group sum (xor 16, 32) -> every lane has the full result.
  acc.x += __shfl_xor(acc.x, 16, 64);
  acc.y += __shfl_xor(acc.y, 16, 64);
  acc.z += __shfl_xor(acc.z, 16, 64);
  acc.w += __shfl_xor(acc.w, 16, 64);
  acc.x += __shfl_xor(acc.x, 32, 64);
  acc.y += __shfl_xor(acc.y, 32, 64);
  acc.z += __shfl_xor(acc.z, 32, 64);
  acc.w += __shfl_xor(acc.w, 32, 64);
  acc.x *= inv; acc.y *= inv; acc.z *= inv; acc.w *= inv;

  if (g == 0) {
    ((float4*)(out + ((size_t)bq * NHH + e) * HH))[c] = acc;
  }
}

extern "C" void kernel_launch(void* const* d_in, const int* in_sizes, int n_in,
                              void* d_out, int out_size, void* d_ws,
                              size_t ws_size, hipStream_t stream) {
  const float* q = (const float*)d_in[0];
  const float* k = (const float*)d_in[1];
  const float* v = (const float*)d_in[2];
  const int* idx = (const int*)d_in[3];
  float* out = (float*)d_out;

  // B*S*NH = 32768 waves; 4 waves per 256-thread block -> 8192 blocks.
  const int n_blocks = (BB * SS * NHH) / 4;
  rand_attn_kernel<<<n_blocks, 256, 0, stream>>>(q, k, v, idx, out);
}